// Round 13
// baseline (280.670 us; speedup 1.0000x reference)
//
#include <hip/hip_runtime.h>
#include <hip/hip_bf16.h>
#include <math.h>

typedef __attribute__((ext_vector_type(8))) short bfrag;   // 8 bf16 (16B)
typedef __attribute__((ext_vector_type(4))) float ffrag;   // mfma acc
typedef __attribute__((ext_vector_type(4))) float f4v;

#define C3 1536   // 3*H*D
#define PS 24     // P LDS row stride (shorts)
#define QKS 1032  // sQK row stride in shorts (1024 + 8 pad: rows n,n+8 2-way alias = free)

__device__ __forceinline__ unsigned short f2bf(float f) {
    unsigned u = __float_as_uint(f);
    return (unsigned short)((u + 0x7FFFu + ((u >> 16) & 1u)) >> 16);  // RNE
}

// sum over the 16 lanes of a DPP row
__device__ __forceinline__ float row16_sum(float x) {
    int v;
    v = __builtin_amdgcn_update_dpp(0, __float_as_int(x), 0xB1, 0xF, 0xF, true);
    x += __int_as_float(v);
    v = __builtin_amdgcn_update_dpp(0, __float_as_int(x), 0x4E, 0xF, 0xF, true);
    x += __int_as_float(v);
    v = __builtin_amdgcn_update_dpp(0, __float_as_int(x), 0x124, 0xF, 0xF, true);
    x += __int_as_float(v);
    v = __builtin_amdgcn_update_dpp(0, __float_as_int(x), 0x128, 0xF, 0xF, true);
    x += __int_as_float(v);
    return x;
}

// ---------- kernel 1: cqkv bf16 rows [q' 512 | k 512 | v 512] (blocks 0..1535)
//            + pqf A/B-frag pos table + pvb B-frag pv table + gbtab (blocks 1536..1631) ----------
__global__ __launch_bounds__(256) void precompute_kernel(
    const float* __restrict__ char_emb, const float* __restrict__ Wc, const float* __restrict__ bc,
    const float* __restrict__ Wp, const float* __restrict__ bp,
    const float* __restrict__ gamma, const float* __restrict__ beta,
    unsigned short* __restrict__ cqkv, unsigned short* __restrict__ pqf,
    unsigned short* __restrict__ pvb, float* __restrict__ gbtab)
{
    const int b = blockIdx.x;
    const int t = threadIdx.x;
    if (b < 1536) {
        const int mt = b / 6;
        const int nt = b - mt * 6;
        const int m0 = mt * 8;
        const int c = nt * 256 + t;
        const float qs = (c < 512) ? 0.125f : 1.f;   // bake 1/TEMP into q
        const float bias = bc[c];
        float acc[8];
        #pragma unroll
        for (int r = 0; r < 8; ++r) acc[r] = bias;
        #pragma unroll 16
        for (int dd = 0; dd < 64; ++dd) {
            const float wv = Wc[dd * C3 + c];
            #pragma unroll
            for (int r = 0; r < 8; ++r)
                acc[r] = fmaf(char_emb[(m0 + r) * 64 + dd], wv, acc[r]);  // uniform -> s_load
        }
        #pragma unroll
        for (int r = 0; r < 8; ++r)
            cqkv[(size_t)(m0 + r) * C3 + c] = f2bf(acc[r] * qs);
    } else {                             // one (l, cc) pair per block
        const int e = b - 1536;
        const int l = e / 6;
        const int cc = e - l * 6;
        if (b == 1536 && t < 64) {       // gbtab[n][0..3]=gamma dt, [4..7]=beta dt
            #pragma unroll
            for (int dt = 0; dt < 4; ++dt) {
                gbtab[t * 8 + dt]     = gamma[dt * 16 + t];
                gbtab[t * 8 + 4 + dt] = beta[dt * 16 + t];
            }
        }
        __shared__ float spos[64];
        if (t < 64) {
            const int f = t & 31;
            const float inv = exp2f(-(float)f * 0.41524101186092034f);
            const float ph = (float)l * inv;
            spos[t] = (t < 32) ? cosf(ph) : sinf(ph);
        }
        __syncthreads();
        const int c = t + cc * 256;
        float acc = bp[c];
        #pragma unroll
        for (int dd = 0; dd < 64; ++dd)
            acc = fmaf(spos[dd], Wp[dd * C3 + c], acc);
        if (c < 1024) {                  // pq'(x1/8)/pk in A/B-frag layout: lane=quad*16+n reads 16B
            const float qs = (c < 512) ? 0.125f : 1.f;
            const int s = c >> 9, h = (c >> 6) & 7, d = c & 63;
            pqf[s * 8192 + ((h * 2 + (d >> 5)) * 64 + ((d >> 3) & 3) * 16 + l) * 8 + (d & 7)]
                = f2bf(acc * qs);
        } else {                         // pv B-frag table
            const int h = (c >> 6) & 7, d = c & 63;
            pvb[((h * 4 + (d >> 4)) * 2 + (l >> 3)) * 128 + (d & 15) * 8 + (l & 7)] = f2bf(acc);
        }
    }
}

// ---------- kernel 2: block-per-word (512 thr, wave=head), COALESCED staging + MLP ----------
__global__ __launch_bounds__(512, 4) void attn_kernel(
    const unsigned short* __restrict__ cqkv, const unsigned short* __restrict__ pqf,
    const unsigned short* __restrict__ pvb, const int* __restrict__ char_code,
    const float* __restrict__ gbtab,
    const float* __restrict__ W1, const float* __restrict__ b1,
    const float* __restrict__ W2, const float* __restrict__ b2,
    float* __restrict__ x)
{
    __shared__ __attribute__((aligned(16))) unsigned char sBuf[55552];
    __shared__ float sWb[280];
    unsigned short* sQK = (unsigned short*)sBuf;              // 16 x QKS shorts = 33024 B
    unsigned short* sVt = (unsigned short*)(sBuf + 33024);    // 16384 B
    unsigned short* sP  = (unsigned short*)(sBuf + 49408);    //  6144 B
    float* sPool = (float*)sBuf;                              //  2048 B (overlay, post-barrier)
    float* sHid  = (float*)(sBuf + 2048);                     //  4352 B (overlay)

    const int t = threadIdx.x;
    const int lane = t & 63;
    const int h = t >> 6;          // wave id = head
    const int w = blockIdx.x;
    const int quad = lane >> 4;
    const int n = lane & 15;
    const int q2 = quad & 1;

    if (t < 128) { sWb[t] = W1[t]; sWb[144 + t] = W2[t]; }
    else if (t < 144) sWb[t] = b1[t - 128];
    else if (t < 152) sWb[272 + (t - 144)] = b2[t - 144];

    const int code = char_code[w * 16 + n];     // 64B region, coalesced
    const bool kvalid = (code != 0);
    const unsigned long long msk = __ballot(kvalid);
    const int nv = __popcll(msk & 0xFFFFull);

    const f4v g4 = *(const f4v*)(gbtab + n * 8);
    const f4v b4 = *(const f4v*)(gbtab + n * 8 + 4);

    // ---- COALESCED staging: wave h copies rows h and h+8 (3KB each, 1KB/wave-load) ----
    #pragma unroll
    for (int r = 0; r < 2; ++r) {
        const int row = h + r * 8;
        const int rcode = __shfl(code, row);                    // wave-uniform row code
        const unsigned short* base = cqkv + (size_t)rcode * C3;
        // q,k sections -> straight rows in sQK
        #pragma unroll
        for (int c = 0; c < 2; ++c)
            *(bfrag*)(sQK + row * QKS + c * 512 + lane * 8)
                = *(const bfrag*)(base + c * 512 + lane * 8);
        // v section -> swizzled B-frag tile (lane holds v[row][d0..d0+7] of head lane>>3)
        const bfrag vv = *(const bfrag*)(base + 1024 + lane * 8);
        const int vh = lane >> 3, d0 = (lane & 7) * 8;
        #pragma unroll
        for (int j = 0; j < 8; ++j) {
            const int d = d0 + j;
            const int e = vh * 1024 + ((d >> 4) * 2 + (row >> 3)) * 128
                        + ((d & 15) ^ ((row >> 3) << 2)) * 8 + (row & 7);
            sVt[e] = (unsigned short)vv[j];
        }
    }
    __syncthreads();

    // ---- S = cq'·ck + cq'·pk + ck·pq' + pq'·pk (q/k from LDS, pos frags coalesced global) ----
    ffrag accS = {0.f, 0.f, 0.f, 0.f};
    {
        const unsigned short* qrow = sQK + n * QKS + h * 64;
        #pragma unroll
        for (int cc = 0; cc < 2; ++cc) {
            const int off = quad * 8 + cc * 32;
            const bfrag cqF = *(const bfrag*)(qrow + off);
            const bfrag ckF = *(const bfrag*)(qrow + 512 + off);
            const bfrag pqF = *(const bfrag*)(pqf + ((h * 2 + cc) * 64 + lane) * 8);
            const bfrag pkF = *(const bfrag*)(pqf + 8192 + ((h * 2 + cc) * 64 + lane) * 8);
            accS = __builtin_amdgcn_mfma_f32_16x16x32_bf16(cqF, ckF, accS, 0, 0, 0);
            accS = __builtin_amdgcn_mfma_f32_16x16x32_bf16(cqF, pkF, accS, 0, 0, 0);
            accS = __builtin_amdgcn_mfma_f32_16x16x32_bf16(ckF, pqF, accS, 0, 0, 0);
            accS = __builtin_amdgcn_mfma_f32_16x16x32_bf16(pqF, pkF, accS, 0, 0, 0);
        }
    }

    // ---- softmax (no max-sub; logits ~1e-5), UNNORMALIZED P (1/sm cancels in LN) ----
    unsigned short* pt = sP + h * 16 * PS;      // wave-private
    #pragma unroll
    for (int r = 0; r < 4; ++r) {
        const float pr = kvalid ? __expf(accS[r]) : 0.f;
        pt[(quad * 4 + r) * PS + n] = f2bf(pr);
    }

    // ---- O = P·cv (sVt) + P·pv (coalesced B-frag) ; sm via ones-MFMA ----
    bfrag ap;
    #pragma unroll
    for (int j = 0; j < 8; ++j) ap[j] = 0;
    if (quad < 2) ap = *(const bfrag*)(pt + n * PS + quad * 8);
    unsigned short* vt = sVt + h * 1024;
    ffrag accO[4];
    #pragma unroll
    for (int dt = 0; dt < 4; ++dt) { ffrag z = {0.f,0.f,0.f,0.f}; accO[dt] = z; }
    #pragma unroll
    for (int dt = 0; dt < 4; ++dt) {
        const bfrag bcv = *(const bfrag*)(vt + (dt * 2 + q2) * 128 + (n ^ (q2 << 2)) * 8);
        accO[dt] = __builtin_amdgcn_mfma_f32_16x16x32_bf16(ap, bcv, accO[dt], 0, 0, 0);
        const bfrag bpv = *(const bfrag*)(pvb + ((h * 4 + dt) * 2 + q2) * 128 + n * 8);
        accO[dt] = __builtin_amdgcn_mfma_f32_16x16x32_bf16(ap, bpv, accO[dt], 0, 0, 0);
    }
    bfrag onesf;
    #pragma unroll
    for (int j = 0; j < 8; ++j) onesf[j] = (short)0x3F80;
    ffrag accE = {0.f, 0.f, 0.f, 0.f};
    accE = __builtin_amdgcn_mfma_f32_16x16x32_bf16(ap, onesf, accE, 0, 0, 0);

    // ---- LayerNorm (O = sm*O_ref; eps scaled by sm^2) + masked pool over i ----
    float ps1[4], ps2[4];
    #pragma unroll
    for (int r = 0; r < 4; ++r) {
        ps1[r] = accO[0][r] + accO[1][r] + accO[2][r] + accO[3][r];
        ps2[r] = accO[0][r]*accO[0][r] + accO[1][r]*accO[1][r]
               + accO[2][r]*accO[2][r] + accO[3][r]*accO[3][r];
        ps1[r] = row16_sum(ps1[r]);
        ps2[r] = row16_sum(ps2[r]);
    }
    float pool[4] = {0.f, 0.f, 0.f, 0.f};
    #pragma unroll
    for (int r = 0; r < 4; ++r) {
        const float mu   = ps1[r] * 0.015625f;
        const float var  = fmaxf(ps2[r] * 0.015625f - mu * mu, 0.f);
        const float rstd = rsqrtf(var + accE[r] * accE[r] * 1e-5f);
        const float iv = ((msk >> (quad * 4 + r)) & 1ull) ? 1.f : 0.f;
        #pragma unroll
        for (int dt = 0; dt < 4; ++dt)
            pool[dt] += iv * fmaf((accO[dt][r] - mu) * rstd, g4[dt], b4[dt]);
    }
    #pragma unroll
    for (int xm = 16; xm <= 32; xm <<= 1) {
        #pragma unroll
        for (int dt = 0; dt < 4; ++dt) pool[dt] += __shfl_xor(pool[dt], xm);
    }
    const float invnv = 1.f / (float)nv;

    __syncthreads();   // all waves done with sQK/sVt/sP -> safe to overlay
    if (quad == 0) {
        #pragma unroll
        for (int dt = 0; dt < 4; ++dt)
            sPool[h * 64 + n * 4 + dt] = pool[dt] * invnv;   // [h][n][dt]
    }
    __syncthreads();

    // ---- MLP: hidden per d (t<64), then 1 output/thread, coalesced 2KB store ----
    if (t < 64) {
        const int dmap = (t & 15) * 4 + (t >> 4);
        float pl[8];
        #pragma unroll
        for (int hh = 0; hh < 8; ++hh) pl[hh] = sPool[hh * 64 + dmap];
        #pragma unroll
        for (int c = 0; c < 16; ++c) {
            float hs = sWb[128 + c];
            #pragma unroll
            for (int hh = 0; hh < 8; ++hh) hs = fmaf(pl[hh], sWb[hh * 16 + c], hs);
            sHid[t * 17 + c] = fmaxf(hs, 0.f);
        }
    }
    __syncthreads();
    {
        const int d = t >> 3, o = t & 7;
        float a = sWb[272 + o];
        #pragma unroll
        for (int c = 0; c < 16; ++c)
            a = fmaf(sHid[d * 17 + c], sWb[144 + c * 8 + o], a);
        x[(size_t)w * 512 + t] = a;
    }
}

// ---------- kernel 3: per-name word average (wave per name, no barriers) ----------
__global__ __launch_bounds__(256) void name_avg_kernel(
    const float* __restrict__ x, const int* __restrict__ word_code,
    const int* __restrict__ n_words, float* __restrict__ out)
{
    const int t = threadIdx.x;
    const int lane = t & 63;
    const int nm = blockIdx.x * 4 + (t >> 6);

    int part = 0;
    for (int i = lane; i < nm; i += 64) part += n_words[i];
    #pragma unroll
    for (int xm = 1; xm <= 32; xm <<= 1) part += __shfl_xor(part, xm);
    const int off = part;
    const int cnt = n_words[nm];

    f4v a0 = {0.f,0.f,0.f,0.f}, a1 = {0.f,0.f,0.f,0.f};
    for (int r = 0; r < cnt; ++r) {
        const int wc = word_code[off + r];
        const f4v u0 = *(const f4v*)(x + (size_t)wc * 512 + lane * 8);
        const f4v u1 = *(const f4v*)(x + (size_t)wc * 512 + lane * 8 + 4);
        #pragma unroll
        for (int k = 0; k < 4; ++k) { a0[k] += u0[k]; a1[k] += u1[k]; }
    }
    const float inv = 1.f / (float)cnt;
    #pragma unroll
    for (int k = 0; k < 4; ++k) { a0[k] *= inv; a1[k] *= inv; }
    *(f4v*)(out + (size_t)nm * 512 + lane * 8) = a0;
    *(f4v*)(out + (size_t)nm * 512 + lane * 8 + 4) = a1;
}

extern "C" void kernel_launch(void* const* d_in, const int* in_sizes, int n_in,
                              void* d_out, int out_size, void* d_ws, size_t ws_size,
                              hipStream_t stream) {
    (void)in_sizes; (void)n_in; (void)out_size; (void)ws_size;
    const float* char_emb = (const float*)d_in[0];
    const float* Wc    = (const float*)d_in[1];
    const float* bc    = (const float*)d_in[2];
    const float* Wp    = (const float*)d_in[3];
    const float* bp    = (const float*)d_in[4];
    const float* gamma = (const float*)d_in[5];
    const float* beta  = (const float*)d_in[6];
    const float* W1    = (const float*)d_in[7];
    const float* b1    = (const float*)d_in[8];
    const float* W2    = (const float*)d_in[9];
    const float* b2    = (const float*)d_in[10];
    const int* char_code = (const int*)d_in[11];
    const int* word_code = (const int*)d_in[12];
    const int* n_words   = (const int*)d_in[13];   // harness passes ints as int32

    char* ws = (char*)d_ws;
    unsigned short* cqkv = (unsigned short*)ws;                 //  6,291,456 B
    unsigned short* pqf  = (unsigned short*)(ws + 6291456);     //     32,768 B
    unsigned short* pvb  = (unsigned short*)(ws + 6324224);     //     16,384 B
    float* x     = (float*)(ws + 6340608);                      // 16,777,216 B
    float* gbtab = (float*)(ws + 23117824);                     //      2,048 B
    float* out = (float*)d_out;

    precompute_kernel<<<1632, 256, 0, stream>>>(char_emb, Wc, bc, Wp, bp, gamma, beta,
                                                cqkv, pqf, pvb, gbtab);
    attn_kernel<<<8192, 512, 0, stream>>>(cqkv, pqf, pvb, char_code, gbtab,
                                          W1, b1, W2, b2, x);
    name_avg_kernel<<<512, 256, 0, stream>>>(x, word_code, n_words, out);
}